// Round 1
// 3205.758 us; speedup vs baseline: 1.9679x; 1.9679x over previous
//
#include <hip/hip_runtime.h>
#include <math.h>

namespace {
constexpr int kB = 2, kT = 1024, kE = 768, kH = 12, kL = 4, kV = 50257;
constexpr int kHD = 64;
constexpr int kM = kB * kT;   // 2048 rows
constexpr int kFF = 4 * kE;   // 3072
constexpr float kEPS = 1e-3f;
constexpr float kSCALE = 0.03608439182435161f;  // 768^-0.5 (reference scales by E, not HD)
}

typedef __bf16 bf16x8 __attribute__((ext_vector_type(8)));
typedef float f32x4 __attribute__((ext_vector_type(4)));
typedef unsigned short u16;

// Split fp32 into hi/lo bf16 (as top-16-bit patterns). x == hi + lo + O(2^-16 x).
__device__ __forceinline__ void split_f(float x, unsigned &hb, unsigned &lb) {
  unsigned xb = __float_as_uint(x);
  hb = xb & 0xFFFF0000u;
  lb = __float_as_uint(x - __uint_as_float(hb)) & 0xFFFF0000u;
}
// pack two top-bit bf16 patterns into one u32 (b0 -> low half, b1 -> high half)
__device__ __forceinline__ unsigned pk(unsigned b0, unsigned b1) {
  return (b0 >> 16) | b1;
}

// x[b,t,:] = tok_emb[tokens[b,t],:] + pos_emb[t,:]
__global__ __launch_bounds__(256) void embed_kernel(
    const int* __restrict__ tokens, const float* __restrict__ tok_emb,
    const float* __restrict__ pos_emb, float* __restrict__ x) {
  int gid = blockIdx.x * 256 + threadIdx.x;  // over kM*kE/4
  int m = gid / (kE / 4);
  int c = gid % (kE / 4);
  int t = m % kT;
  int tok = tokens[m];
  float4 a = ((const float4*)tok_emb)[(size_t)tok * (kE / 4) + c];
  float4 b = ((const float4*)pos_emb)[(size_t)t * (kE / 4) + c];
  ((float4*)x)[gid] = make_float4(a.x + b.x, a.y + b.y, a.z + b.z, a.w + b.w);
}

// one block (256 thr) per row of E=768: 3 elements/thread
__global__ __launch_bounds__(256) void ln_kernel(
    const float* __restrict__ x, const float* __restrict__ g,
    const float* __restrict__ bta, float* __restrict__ out) {
  __shared__ float ssum[256], ssq[256];
  int row = blockIdx.x, tid = threadIdx.x;
  const float* xr = x + (size_t)row * kE;
  float v0 = xr[tid], v1 = xr[tid + 256], v2 = xr[tid + 512];
  ssum[tid] = v0 + v1 + v2;
  ssq[tid] = v0 * v0 + v1 * v1 + v2 * v2;
  __syncthreads();
  for (int off = 128; off > 0; off >>= 1) {
    if (tid < off) { ssum[tid] += ssum[tid + off]; ssq[tid] += ssq[tid + off]; }
    __syncthreads();
  }
  float mu = ssum[0] * (1.f / kE);
  float var = ssq[0] * (1.f / kE) - mu * mu;
  float rstd = rsqrtf(var + kEPS);
  float* orow = out + (size_t)row * kE;
  orow[tid]       = (v0 - mu) * rstd * g[tid]       + bta[tid];
  orow[tid + 256] = (v1 - mu) * rstd * g[tid + 256] + bta[tid + 256];
  orow[tid + 512] = (v2 - mu) * rstd * g[tid + 512] + bta[tid + 512];
}

// Split-bf16 MFMA GEMM: C = (addsrc?) + A[M,K] @ W[K,N] + (bias?), optional ReLU.
// fp32 emulated as hi+lo bf16, 3 MFMA products (hi*hi + lo*hi + hi*lo).
// Block: BN=128 cols, BM=WMF*32 rows, 256 thr = 4 waves in 2x2; wave tile (WMF*16)x64.
// BK=32 (one 16x16x32 MFMA K-slab per step). K%32==0, M%BM==0 assumed; N guarded.
// LDS rows padded to 40 bf16 (80B = 20 banks): even bank spread for ds_read_b128
// frag reads AND staging writes (checked: 8 lanes per 16B window).
template <int WMF, int RELU>
__global__ __launch_bounds__(256) void gemm_mfma_kernel(
    const float* __restrict__ A, const float* __restrict__ W,
    const float* __restrict__ bias, const float* __restrict__ addsrc,
    float* __restrict__ C, int N, int K) {
  constexpr int BM = WMF * 32;
  __shared__ __align__(16) u16 Ahi[BM][40], Alo[BM][40];
  __shared__ __align__(16) u16 Whi[128][40], Wlo[128][40];
  const int tid = threadIdx.x;
  const int lane = tid & 63;
  const int w = tid >> 6;
  const int wm = (w >> 1) * (WMF * 16);  // wave row offset
  const int wn = (w & 1) * 64;           // wave col offset
  const int m0 = blockIdx.y * BM, n0 = blockIdx.x * 128;
  const int fr = lane & 15, fg = lane >> 4;  // frag row/col, k-group

  // W staging: thread owns one n-column (tid&127) x 16 k's ((tid>>7)*16 .. +15)
  const int wnl = tid & 127;
  const int wkh = tid >> 7;
  const bool wok = (n0 + wnl) < N;
  constexpr int AF4 = BM / 32;  // float4 A-loads per thread

  f32x4 acc[WMF][4];
#pragma unroll
  for (int i = 0; i < WMF; ++i)
#pragma unroll
    for (int j = 0; j < 4; ++j) acc[i][j] = f32x4{0.f, 0.f, 0.f, 0.f};

  float4 aR[AF4];
  float wR[16];
  // prologue loads (k0 = 0)
#pragma unroll
  for (int q = 0; q < AF4; ++q) {
    int el = tid + q * 256;
    int m = el >> 3, kq = el & 7;
    aR[q] = *(const float4*)&A[(size_t)(m0 + m) * K + kq * 4];
  }
  {
    const float* wp = W + (size_t)(wkh * 16) * N + n0 + wnl;
#pragma unroll
    for (int j = 0; j < 16; ++j) wR[j] = wok ? wp[(size_t)j * N] : 0.f;
  }

  for (int k0 = 0; k0 < K; k0 += 32) {
    __syncthreads();  // previous frag reads done -> LDS writable
    // ---- convert + stage to LDS ----
#pragma unroll
    for (int q = 0; q < AF4; ++q) {
      int el = tid + q * 256;
      int m = el >> 3, kq = el & 7;
      unsigned h0, l0, h1, l1, h2, l2, h3, l3;
      split_f(aR[q].x, h0, l0); split_f(aR[q].y, h1, l1);
      split_f(aR[q].z, h2, l2); split_f(aR[q].w, h3, l3);
      *(uint2*)&Ahi[m][kq * 4] = make_uint2(pk(h0, h1), pk(h2, h3));
      *(uint2*)&Alo[m][kq * 4] = make_uint2(pk(l0, l1), pk(l2, l3));
    }
    {
      unsigned hh[16], ll[16];
#pragma unroll
      for (int j = 0; j < 16; ++j) split_f(wR[j], hh[j], ll[j]);
#pragma unroll
      for (int u = 0; u < 2; ++u) {
        *(uint4*)&Whi[wnl][wkh * 16 + u * 8] = make_uint4(
            pk(hh[u * 8 + 0], hh[u * 8 + 1]), pk(hh[u * 8 + 2], hh[u * 8 + 3]),
            pk(hh[u * 8 + 4], hh[u * 8 + 5]), pk(hh[u * 8 + 6], hh[u * 8 + 7]));
        *(uint4*)&Wlo[wnl][wkh * 16 + u * 8] = make_uint4(
            pk(ll[u * 8 + 0], ll[u * 8 + 1]), pk(ll[u * 8 + 2], ll[u * 8 + 3]),
            pk(ll[u * 8 + 4], ll[u * 8 + 5]), pk(ll[u * 8 + 6], ll[u * 8 + 7]));
      }
    }
    __syncthreads();
    // ---- prefetch next K-slab into regs (hides HBM latency under MFMAs) ----
    if (k0 + 32 < K) {
#pragma unroll
      for (int q = 0; q < AF4; ++q) {
        int el = tid + q * 256;
        int m = el >> 3, kq = el & 7;
        aR[q] = *(const float4*)&A[(size_t)(m0 + m) * K + (k0 + 32) + kq * 4];
      }
      const float* wp = W + (size_t)(k0 + 32 + wkh * 16) * N + n0 + wnl;
#pragma unroll
      for (int j = 0; j < 16; ++j) wR[j] = wok ? wp[(size_t)j * N] : 0.f;
    }
    // ---- frags + MFMA ----
    // A-frag lane l: row=l&15, k=8*(l>>4)+j. B-frag: col=l&15, same k order
    // (same k-permutation on both operands => result invariant to exact order).
    bf16x8 ah[WMF], al[WMF];
#pragma unroll
    for (int mi = 0; mi < WMF; ++mi) {
      ah[mi] = *(const bf16x8*)&Ahi[wm + mi * 16 + fr][fg * 8];
      al[mi] = *(const bf16x8*)&Alo[wm + mi * 16 + fr][fg * 8];
    }
#pragma unroll
    for (int nj = 0; nj < 4; ++nj) {
      bf16x8 bh = *(const bf16x8*)&Whi[wn + nj * 16 + fr][fg * 8];
      bf16x8 bl = *(const bf16x8*)&Wlo[wn + nj * 16 + fr][fg * 8];
#pragma unroll
      for (int mi = 0; mi < WMF; ++mi) {
        acc[mi][nj] = __builtin_amdgcn_mfma_f32_16x16x32_bf16(ah[mi], bh, acc[mi][nj], 0, 0, 0);
        acc[mi][nj] = __builtin_amdgcn_mfma_f32_16x16x32_bf16(al[mi], bh, acc[mi][nj], 0, 0, 0);
        acc[mi][nj] = __builtin_amdgcn_mfma_f32_16x16x32_bf16(ah[mi], bl, acc[mi][nj], 0, 0, 0);
      }
    }
  }
  // ---- epilogue: D row=(lane>>4)*4+reg, col=lane&15 (m89-verified) ----
#pragma unroll
  for (int mi = 0; mi < WMF; ++mi) {
#pragma unroll
    for (int nj = 0; nj < 4; ++nj) {
#pragma unroll
      for (int r = 0; r < 4; ++r) {
        int row = m0 + wm + mi * 16 + fg * 4 + r;
        int col = n0 + wn + nj * 16 + fr;
        if (col < N) {
          float v = acc[mi][nj][r];
          if (bias) v += bias[col];
          if (addsrc) v += addsrc[(size_t)row * N + col];
          if (RELU) v = fmaxf(v, 0.f);
          C[(size_t)row * N + col] = v;
        }
      }
    }
  }
}

// Reference quirk: softmax over the QUERY axis. For each (b,h,key j):
// m_j = max_{i>=j} S_ij, l_j = sum_{i>=j} exp(S_ij - m_j).  Online over i-tiles.
__global__ __launch_bounds__(256) void attn_colstats_kernel(
    const float* __restrict__ q, const float* __restrict__ k,
    float* __restrict__ colm, float* __restrict__ coll) {
  __shared__ __align__(16) float ksT[64][68];  // [d][j]
  __shared__ __align__(16) float qsT[64][68];  // [d][i]
  __shared__ float red[16][64];
  __shared__ float cm[64], cl[64];
  int bh = blockIdx.x, jt = blockIdx.y;
  int b = bh / kH, h = bh % kH;
  int tid = threadIdx.x, tx = tid & 15, ty = tid >> 4;
  int j0 = jt * 64;
  size_t base = (size_t)b * kT * kE + h * kHD;
#pragma unroll
  for (int r = 0; r < 4; ++r) {
    int idx = tid + r * 256;
    int jl = idx >> 4, dq = (idx & 15) * 4;
    float4 kv = *(const float4*)&k[base + (size_t)(j0 + jl) * kE + dq];
    ksT[dq + 0][jl] = kv.x; ksT[dq + 1][jl] = kv.y;
    ksT[dq + 2][jl] = kv.z; ksT[dq + 3][jl] = kv.w;
  }
  if (tid < 64) { cm[tid] = -INFINITY; cl[tid] = 0.f; }
  __syncthreads();
  for (int it = jt; it < kT / 64; ++it) {
    int i0 = it * 64;
#pragma unroll
    for (int r = 0; r < 4; ++r) {
      int idx = tid + r * 256;
      int il = idx >> 4, dq = (idx & 15) * 4;
      float4 qv = *(const float4*)&q[base + (size_t)(i0 + il) * kE + dq];
      qsT[dq + 0][il] = qv.x; qsT[dq + 1][il] = qv.y;
      qsT[dq + 2][il] = qv.z; qsT[dq + 3][il] = qv.w;
    }
    __syncthreads();
    float s[4][4] = {};
#pragma unroll 8
    for (int d = 0; d < 64; ++d) {
      float4 a4 = *(const float4*)&qsT[d][ty * 4];
      float4 b4 = *(const float4*)&ksT[d][tx * 4];
      float a[4] = {a4.x, a4.y, a4.z, a4.w};
      float bb[4] = {b4.x, b4.y, b4.z, b4.w};
#pragma unroll
      for (int i = 0; i < 4; ++i)
#pragma unroll
        for (int j = 0; j < 4; ++j) s[i][j] += a[i] * bb[j];
    }
    float tmax[4] = {-INFINITY, -INFINITY, -INFINITY, -INFINITY};
#pragma unroll
    for (int i = 0; i < 4; ++i)
#pragma unroll
      for (int j = 0; j < 4; ++j) {
        bool valid = (i0 + ty * 4 + i) >= (j0 + tx * 4 + j);
        s[i][j] = valid ? s[i][j] * kSCALE : -INFINITY;
        tmax[j] = fmaxf(tmax[j], s[i][j]);
      }
#pragma unroll
    for (int j = 0; j < 4; ++j) red[ty][tx * 4 + j] = tmax[j];
    __syncthreads();
    if (tid < 64) {
      float tm = -INFINITY;
#pragma unroll
      for (int r = 0; r < 16; ++r) tm = fmaxf(tm, red[r][tid]);
      float mo = cm[tid], mn = fmaxf(mo, tm);
      cl[tid] *= __expf(mo - mn);  // exp(-inf)=0 on first tile
      cm[tid] = mn;
    }
    __syncthreads();
    float ps[4] = {0.f, 0.f, 0.f, 0.f};
#pragma unroll
    for (int j = 0; j < 4; ++j) {
      float mj = cm[tx * 4 + j];
#pragma unroll
      for (int i = 0; i < 4; ++i) ps[j] += __expf(s[i][j] - mj);  // masked: exp(-inf)=0
    }
#pragma unroll
    for (int j = 0; j < 4; ++j) red[ty][tx * 4 + j] = ps[j];
    __syncthreads();
    if (tid < 64) {
      float a = 0.f;
#pragma unroll
      for (int r = 0; r < 16; ++r) a += red[r][tid];
      cl[tid] += a;
    }
    __syncthreads();
  }
  if (tid < 64) {
    colm[(size_t)bh * kT + j0 + tid] = cm[tid];
    coll[(size_t)bh * kT + j0 + tid] = cl[tid];
  }
}

// att[b,i,h,:] = sum_{j<=i} exp(S_ij - m_j)/l_j * v[b,j,h,:]
__global__ __launch_bounds__(256) void attn_av_kernel(
    const float* __restrict__ q, const float* __restrict__ k,
    const float* __restrict__ v, const float* __restrict__ colm,
    const float* __restrict__ coll, float* __restrict__ att) {
  __shared__ __align__(16) float qsT[64][68];  // [d][i], loaded once
  __shared__ __align__(16) float ksT[64][68];  // [d][j]; P[j][i] aliases this after use
  __shared__ __align__(16) float Vs[64][64];   // [j][d]
  __shared__ float mjs[64], ljs[64];
  float (*Ps)[68] = ksT;
  int bh = blockIdx.x, it = blockIdx.y;
  int b = bh / kH, h = bh % kH;
  int tid = threadIdx.x, tx = tid & 15, ty = tid >> 4;
  int i0 = it * 64;
  size_t base = (size_t)b * kT * kE + h * kHD;
#pragma unroll
  for (int r = 0; r < 4; ++r) {
    int idx = tid + r * 256;
    int il = idx >> 4, dq = (idx & 15) * 4;
    float4 qv = *(const float4*)&q[base + (size_t)(i0 + il) * kE + dq];
    qsT[dq + 0][il] = qv.x; qsT[dq + 1][il] = qv.y;
    qsT[dq + 2][il] = qv.z; qsT[dq + 3][il] = qv.w;
  }
  float acc[4][4] = {};
  for (int jt = 0; jt <= it; ++jt) {
    int j0 = jt * 64;
#pragma unroll
    for (int r = 0; r < 4; ++r) {
      int idx = tid + r * 256;
      int jl = idx >> 4, dq = (idx & 15) * 4;
      float4 kv = *(const float4*)&k[base + (size_t)(j0 + jl) * kE + dq];
      ksT[dq + 0][jl] = kv.x; ksT[dq + 1][jl] = kv.y;
      ksT[dq + 2][jl] = kv.z; ksT[dq + 3][jl] = kv.w;
      *(float4*)&Vs[jl][dq] = *(const float4*)&v[base + (size_t)(j0 + jl) * kE + dq];
    }
    if (tid < 64) {
      mjs[tid] = colm[(size_t)bh * kT + j0 + tid];
      ljs[tid] = 1.f / coll[(size_t)bh * kT + j0 + tid];
    }
    __syncthreads();
    float s[4][4] = {};
#pragma unroll 8
    for (int d = 0; d < 64; ++d) {
      float4 a4 = *(const float4*)&qsT[d][ty * 4];
      float4 b4 = *(const float4*)&ksT[d][tx * 4];
      float a[4] = {a4.x, a4.y, a4.z, a4.w};
      float bb[4] = {b4.x, b4.y, b4.z, b4.w};
#pragma unroll
      for (int i = 0; i < 4; ++i)
#pragma unroll
        for (int j = 0; j < 4; ++j) s[i][j] += a[i] * bb[j];
    }
    __syncthreads();  // all ksT reads done before P overwrites it
#pragma unroll
    for (int i = 0; i < 4; ++i)
#pragma unroll
      for (int j = 0; j < 4; ++j) {
        bool valid = (i0 + ty * 4 + i) >= (j0 + tx * 4 + j);
        float p = valid ? __expf(s[i][j] * kSCALE - mjs[tx * 4 + j]) * ljs[tx * 4 + j]
                        : 0.f;
        Ps[tx * 4 + j][ty * 4 + i] = p;
      }
    __syncthreads();
#pragma unroll 8
    for (int j = 0; j < 64; ++j) {
      float4 a4 = *(const float4*)&Ps[j][ty * 4];
      float4 b4 = *(const float4*)&Vs[j][tx * 4];
      float a[4] = {a4.x, a4.y, a4.z, a4.w};
      float bb[4] = {b4.x, b4.y, b4.z, b4.w};
#pragma unroll
      for (int i = 0; i < 4; ++i)
#pragma unroll
        for (int d = 0; d < 4; ++d) acc[i][d] += a[i] * bb[d];
    }
    __syncthreads();
  }
#pragma unroll
  for (int i = 0; i < 4; ++i) {
    size_t off = (size_t)(b * kT + i0 + ty * 4 + i) * kE + h * kHD + tx * 4;
    *(float4*)&att[off] = make_float4(acc[i][0], acc[i][1], acc[i][2], acc[i][3]);
  }
}

extern "C" void kernel_launch(void* const* d_in, const int* in_sizes, int n_in,
                              void* d_out, int out_size, void* d_ws, size_t ws_size,
                              hipStream_t stream) {
  const int* tokens    = (const int*)d_in[0];
  const float* tok_emb = (const float*)d_in[1];
  const float* pos_emb = (const float*)d_in[2];
  const float* wq      = (const float*)d_in[3];
  const float* wk      = (const float*)d_in[4];
  const float* wv      = (const float*)d_in[5];
  const float* wo      = (const float*)d_in[6];
  const float* wo_b    = (const float*)d_in[7];
  const float* ln1_g   = (const float*)d_in[8];
  const float* ln1_b   = (const float*)d_in[9];
  const float* ln2_g   = (const float*)d_in[10];
  const float* ln2_b   = (const float*)d_in[11];
  const float* ff1_w   = (const float*)d_in[12];
  const float* ff1_b   = (const float*)d_in[13];
  const float* ff2_w   = (const float*)d_in[14];
  const float* ff2_b   = (const float*)d_in[15];
  const float* lnf_g   = (const float*)d_in[16];
  const float* lnf_b   = (const float*)d_in[17];
  const float* head_w  = (const float*)d_in[18];
  const float* head_b  = (const float*)d_in[19];
  float* out = (float*)d_out;

  float* ws   = (float*)d_ws;
  float* x    = ws;                          // [M,E]
  float* hbuf = x    + (size_t)kM * kE;      // [M,E]
  float* qb   = hbuf + (size_t)kM * kE;      // [M,E]
  float* kb   = qb   + (size_t)kM * kE;      // [M,E]
  float* vb   = kb   + (size_t)kM * kE;      // [M,E]
  float* attb = vb   + (size_t)kM * kE;      // [M,E]
  float* ffb  = attb + (size_t)kM * kE;      // [M,4E]
  float* cm   = ffb  + (size_t)kM * kFF;     // [B*H*T]
  float* cl   = cm   + (size_t)kB * kH * kT; // [B*H*T]

  embed_kernel<<<kM * kE / 4 / 256, 256, 0, stream>>>(tokens, tok_emb, pos_emb, x);

  dim3 gQ(kE / 128, kM / 64);              // (6, 32)  BM=64  BN=128
  dim3 gFF1(kFF / 128, kM / 128);          // (24, 16) BM=128 BN=128
  dim3 gHead((kV + 127) / 128, kM / 128);  // (393, 16)
  dim3 gAtt(kB * kH, kT / 64);             // 24 x 16
  for (int l = 0; l < kL; ++l) {
    ln_kernel<<<kM, 256, 0, stream>>>(x, ln1_g + l * kE, ln1_b + l * kE, hbuf);
    gemm_mfma_kernel<2, 0><<<gQ, 256, 0, stream>>>(hbuf, wq + (size_t)l * kE * kE, nullptr, nullptr, qb, kE, kE);
    gemm_mfma_kernel<2, 0><<<gQ, 256, 0, stream>>>(hbuf, wk + (size_t)l * kE * kE, nullptr, nullptr, kb, kE, kE);
    gemm_mfma_kernel<2, 0><<<gQ, 256, 0, stream>>>(hbuf, wv + (size_t)l * kE * kE, nullptr, nullptr, vb, kE, kE);
    attn_colstats_kernel<<<gAtt, 256, 0, stream>>>(qb, kb, cm, cl);
    attn_av_kernel<<<gAtt, 256, 0, stream>>>(qb, kb, vb, cm, cl, attb);
    gemm_mfma_kernel<2, 0><<<gQ, 256, 0, stream>>>(attb, wo + (size_t)l * kE * kE, wo_b + l * kE, x, x, kE, kE);
    ln_kernel<<<kM, 256, 0, stream>>>(x, ln2_g + l * kE, ln2_b + l * kE, hbuf);
    gemm_mfma_kernel<4, 1><<<gFF1, 256, 0, stream>>>(hbuf, ff1_w + (size_t)l * kE * kFF, ff1_b + l * kFF, nullptr, ffb, kFF, kE);
    gemm_mfma_kernel<2, 0><<<gQ, 256, 0, stream>>>(ffb, ff2_w + (size_t)l * kFF * kE, ff2_b + l * kE, hbuf, x, kE, kFF);
  }
  ln_kernel<<<kM, 256, 0, stream>>>(x, lnf_g, lnf_b, hbuf);
  gemm_mfma_kernel<4, 0><<<gHead, 256, 0, stream>>>(hbuf, head_w, head_b, nullptr, out, kV, kE);
}